// Round 13
// baseline (345.906 us; speedup 1.0000x reference)
//
#include <hip/hip_runtime.h>

#define BATCH 16
#define CCH 512
#define LEN 4096
#define LPAD 4098

typedef unsigned short u16;
typedef __bf16 bf16x8 __attribute__((ext_vector_type(8)));
typedef float f32x4 __attribute__((ext_vector_type(4)));
typedef u16 u16x8 __attribute__((ext_vector_type(8)));
typedef u16 u16x4 __attribute__((ext_vector_type(4)));

__device__ __forceinline__ u16 f2bf(float f) {
    unsigned u = __float_as_uint(f);
    u = (u + 0x7fffu + ((u >> 16) & 1u)) >> 16;
    return (u16)u;
}
__device__ __forceinline__ float bf2f(u16 v) {
    return __uint_as_float(((unsigned)v) << 16);
}
__device__ __forceinline__ float silu_f(float v) {
    return v / (1.f + __expf(-v));
}
__device__ __forceinline__ void async16(const u16* g, u16* l) {
    __builtin_amdgcn_global_load_lds(
        (const __attribute__((address_space(1))) unsigned int*)g,
        (__attribute__((address_space(3))) unsigned int*)l, 16, 0, 0);
}

#define SBAR() __builtin_amdgcn_sched_barrier(0)
#define HWBAR() { SBAR(); __builtin_amdgcn_s_barrier(); SBAR(); }
#define WAIT_LGKM0() { asm volatile("s_waitcnt lgkmcnt(0)" ::: "memory"); SBAR(); }
#define WAIT_VM(n) { asm volatile("s_waitcnt vmcnt(" #n ")" ::: "memory"); SBAR(); }

// ---------------------------------------------------------------------------
__global__ __launch_bounds__(256)
void absmean_partial(const float* __restrict__ w1, const float* __restrict__ w2,
                     float* __restrict__ part) {
    const int tid = threadIdx.x;
    const int base = blockIdx.x * 3072;
    float s1 = 0.f, s2 = 0.f;
    for (int i = tid; i < 3072; i += 256) {
        s1 += fabsf(w1[base + i]);
        s2 += fabsf(w2[base + i]);
    }
    __shared__ float r1[256], r2[256];
    r1[tid] = s1; r2[tid] = s2;
    __syncthreads();
    for (int off = 128; off > 0; off >>= 1) {
        if (tid < off) { r1[tid] += r1[tid + off]; r2[tid] += r2[tid + off]; }
        __syncthreads();
    }
    if (tid == 0) { part[blockIdx.x] = r1[0]; part[256 + blockIdx.x] = r2[0]; }
}

__global__ __launch_bounds__(256)
void finalize_scale(const float* __restrict__ part, float* __restrict__ sv) {
    const int tid = threadIdx.x;
    __shared__ float r1[256], r2[256];
    r1[tid] = part[tid]; r2[tid] = part[256 + tid];
    __syncthreads();
    for (int off = 128; off > 0; off >>= 1) {
        if (tid < off) { r1[tid] += r1[tid + off]; r2[tid] += r2[tid + off]; }
        __syncthreads();
    }
    if (tid == 0) {
        sv[0] = fmaxf(r1[0] * (1.f / 786432.f), 1e-5f);
        sv[1] = fmaxf(r2[0] * (1.f / 786432.f), 1e-5f);
    }
}

// ---------------------------------------------------------------------------
__global__ __launch_bounds__(256)
void quantize_both(const float* __restrict__ w1, const float* __restrict__ w2,
                   const float* __restrict__ sv,
                   u16* __restrict__ wq1, u16* __restrict__ wq2) {
    const int idx = blockIdx.x * 256 + threadIdx.x;   // [0, 786432)
    const float s1 = sv[0], s2 = sv[1];
    const int o   = idx / 1536;
    const int rem = idx - o * 1536;
    const int i   = rem / 3;
    const int k   = rem - i * 3;
    const int dst = k * (CCH * CCH) + o * CCH + i;
    float q1 = fmaxf(-1.f, fminf(1.f, rintf(w1[idx] / s1)));
    float q2 = fmaxf(-1.f, fminf(1.f, rintf(w2[idx] / s2)));
    wq1[dst] = f2bf(q1);
    wq2[dst] = f2bf(q2);
}

__global__ __launch_bounds__(256)
void zero_pads(u16* __restrict__ h, u16* __restrict__ h1) {
    const int idx = blockIdx.x * 256 + threadIdx.x;   // [0, 16384)
    const int b = idx >> 10;
    const int r = (idx >> 9) & 1;
    const int i = idx & 511;
    const size_t off = ((size_t)b * LPAD + (r ? (LPAD - 1) : 0)) * CCH + i;
    h[off] = 0;
    h1[off] = 0;
}

// ---------------------------------------------------------------------------
__global__ __launch_bounds__(256)
void rms_silu_transpose(const float* __restrict__ x, const float* __restrict__ g,
                        u16* __restrict__ h_t) {
    __shared__ u16   xt[CCH][33];
    __shared__ float red[8][32];
    __shared__ float rinv[32];
    const int tid = threadIdx.x;
    const int bb  = blockIdx.x >> 7;
    const int l0  = (blockIdx.x & 127) << 5;

    const size_t xbase = (size_t)bb * CCH * LEN + l0;
    {
        const int i_hi = tid >> 3;
        const int l4   = (tid & 7) << 2;
        #pragma unroll
        for (int it = 0; it < 16; ++it) {
            const int i = it * 32 + i_hi;
            const float4 v = *(const float4*)&x[xbase + (size_t)i * LEN + l4];
            xt[i][l4 + 0] = f2bf(v.x);
            xt[i][l4 + 1] = f2bf(v.y);
            xt[i][l4 + 2] = f2bf(v.z);
            xt[i][l4 + 3] = f2bf(v.w);
        }
    }
    __syncthreads();
    {
        const int l = tid & 31, seg = tid >> 5;
        const int ibeg = seg * 64;
        float ss = 0.f;
        #pragma unroll 8
        for (int i = ibeg; i < ibeg + 64; ++i) {
            const float v = bf2f(xt[i][l]);
            ss += v * v;
        }
        red[seg][l] = ss;
    }
    __syncthreads();
    if (tid < 32) {
        float tot = 0.f;
        #pragma unroll
        for (int k2 = 0; k2 < 8; ++k2) tot += red[k2][tid];
        rinv[tid] = rsqrtf(tot * (1.f / 512.f) + 1e-6f);
    }
    __syncthreads();
    {
        const int l  = tid >> 3;
        const int i0 = (tid & 7) << 6;
        const float ri = rinv[l];
        const size_t ob = ((size_t)bb * LPAD + l0 + l + 1) * CCH + i0;
        for (int ii = 0; ii < 64; ii += 8) {
            u16x8 ov;
            #pragma unroll
            for (int jj = 0; jj < 8; ++jj) {
                const int i = i0 + ii + jj;
                float v = bf2f(xt[i][l]) * ri * g[i];
                ov[jj] = f2bf(silu_f(v));
            }
            *(u16x8*)&h_t[ob + ii] = ov;
        }
    }
}

// ---------------------------------------------------------------------------
// Conv-as-GEMM, R6 chassis at BK=32 for 2 blocks/CU (desync barrier domains).
// 256x256 tile, 1024 threads = 16 waves (4M x 4N), per-wave 64x64 (4x4 frags).
// Double-buffered LDS 2 x 32 KiB = 64 KiB -> 2 blocks/CU, 8 waves/SIMD.
// 48 K-steps (ks-inner), one barrier per step, vm0 cadence (R6-proven).
// Swizzle (BK=32, 64B rows): chunk' = (lane>>4) ^ (lane&3) on read; staging
// source col pre-swizzled with the same involution; bank-uniform (8 wd/bank).
template<int EPI>
__global__ __launch_bounds__(1024)
void conv_gemm13(const u16* __restrict__ Bsrc, const u16* __restrict__ Wq,
                 const float* __restrict__ sptr, const float* __restrict__ bias,
                 const float* __restrict__ resid, u16* __restrict__ outb,
                 float* __restrict__ outf) {
    extern __shared__ u16 lds[];          // 32768 u16 = 64 KiB
    const int tid  = threadIdx.x;
    const int lane = tid & 63;
    const int wave = tid >> 6;
    const int wm = wave >> 2;             // 0..3  (M quarter)
    const int wn = wave & 3;              // 0..3  (N quarter)

    // T1: bijective XCD chunking (512 = 8 x 64); mt-pairs share a B-panel.
    const int wgid = (blockIdx.x & 7) * 64 + (blockIdx.x >> 3);
    const int mt = wgid & 1;
    const int nt = wgid >> 1;
    const int o0 = mt << 8;
    const int bb = nt >> 4;
    const int l0 = (nt & 15) << 8;

    // staging: 256 rows x 32 cols per matrix; thread -> row tid>>2,
    // chunk tid&3; source col pre-swizzled: (c ^ (row&3))*8
    const int srow = tid >> 2;                                  // 0..255
    const int scol = (((tid & 3) ^ (srow & 3)) << 3);
    const int sdst = tid << 3;                                  // u16 units

    const u16* aSrcBase = Wq + (size_t)(o0 + srow) * CCH + scol;
    const u16* bSrcBase = Bsrc + ((size_t)bb * LPAD + l0 + srow) * CCH + scol;

    // stage K-step (ks2, i02) into buffer pb: A 16KB + B 16KB (2 async16/thr)
    auto stage_full = [&](int pb, int ks2, int i02) {
        async16(aSrcBase + ks2 * (CCH * CCH) + i02, &lds[pb * 16384 + sdst]);
        async16(bSrcBase + (size_t)ks2 * CCH + i02,
                &lds[pb * 16384 + 8192 + sdst]);
    };

    // read geometry: row = base + lane&15, k-chunk q = lane>>4,
    // lds chunk' = q ^ (row&3) = (lane>>4) ^ (lane&3)
    const int cc = (((lane >> 4) ^ (lane & 3)) << 3);
    const int aB = (wm * 64 + (lane & 15)) * 32 + cc;           // + m*512
    const int bB = 8192 + (wn * 64 + (lane & 15)) * 32 + cc;    // + n*512

    f32x4 acc[4][4];
    #pragma unroll
    for (int m = 0; m < 4; ++m)
        #pragma unroll
        for (int n = 0; n < 4; ++n)
            acc[m][n] = (f32x4){0.f, 0.f, 0.f, 0.f};

    stage_full(0, 0, 0);
    WAIT_VM(0);
    HWBAR();

    int ks = 0, i0 = 0;
    for (int t = 0; t < 48; ++t) {
        const int cur = t & 1;
        const int cb = cur * 16384;
        int ksn = ks + 1, i0n = i0;
        if (ksn == 3) { ksn = 0; i0n += 32; }
        if (t < 47) stage_full(cur ^ 1, ksn, i0n);   // prefetch next tile
        bf16x8 ar[4], br[4];
        #pragma unroll
        for (int m = 0; m < 4; ++m)
            ar[m] = *(const bf16x8*)&lds[cb + aB + m * 512];
        #pragma unroll
        for (int n = 0; n < 4; ++n)
            br[n] = *(const bf16x8*)&lds[cb + bB + n * 512];
        __builtin_amdgcn_s_setprio(1);
        #pragma unroll
        for (int m = 0; m < 4; ++m)
            #pragma unroll
            for (int n = 0; n < 4; ++n)
                acc[m][n] = __builtin_amdgcn_mfma_f32_16x16x32_bf16(
                    ar[m], br[n], acc[m][n], 0, 0, 0);
        __builtin_amdgcn_s_setprio(0);
        WAIT_LGKM0();                  // reads of buf[cur] retired (WAR safety)
        if (t < 47) { WAIT_VM(0); }    // next tile landed
        HWBAR();
        ks = ksn; i0 = i0n;
    }

    // epilogue
    const float sc = sptr[0];

    if (EPI == 1) {
        // two half-passes of 128 l-rows each (64 KB LDS scratch budget):
        // silu(sc*acc+bias) -> lds[(l&127)][o] bf16 swizzled, then coalesced
        // 16B stores (8 threads cover 128B contiguous).
        #pragma unroll
        for (int pass = 0; pass < 2; ++pass) {
            if ((wn >> 1) == pass) {
                #pragma unroll
                for (int m = 0; m < 4; ++m) {
                    const int o_loc = wm * 64 + m * 16 + ((lane >> 4) << 2);
                    const int ob = o0 + o_loc;
                    const float b0 = bias[ob + 0], b1 = bias[ob + 1];
                    const float b2 = bias[ob + 2], b3 = bias[ob + 3];
                    #pragma unroll
                    for (int n = 0; n < 4; ++n) {
                        const int l_loc = (wn & 1) * 64 + n * 16 + (lane & 15);
                        const f32x4 a = acc[m][n];
                        u16x4 ov;
                        ov[0] = f2bf(silu_f(sc * a[0] + b0));
                        ov[1] = f2bf(silu_f(sc * a[1] + b1));
                        ov[2] = f2bf(silu_f(sc * a[2] + b2));
                        ov[3] = f2bf(silu_f(sc * a[3] + b3));
                        char* p = (char*)lds + l_loc * 512 +
                                  (((unsigned)(o_loc << 1)) ^ ((l_loc & 7) << 4));
                        *(u16x4*)p = ov;
                    }
                }
            }
            __syncthreads();
            {
                const int row = tid >> 3;            // 0..127
                const int ch0 = tid & 7;             // 16B slot within row
                u16* gdst = outb +
                    ((size_t)bb * LPAD + l0 + pass * 128 + row + 1) * CCH + o0;
                char* srp = (char*)lds + row * 512;
                const int swz2 = (row & 7) << 4;
                #pragma unroll
                for (int c = 0; c < 4; ++c) {
                    const int slot = c * 8 + ch0;    // 0..31 (16B units)
                    const uint4 v = *(const uint4*)(srp + ((slot * 16) ^ swz2));
                    *(uint4*)(gdst + slot * 8) = v;
                }
            }
            __syncthreads();
        }
    } else {
        const int lbase = l0 + wn * 64 + (lane & 15);
        const int obase = o0 + wm * 64 + ((lane >> 4) << 2);
        #pragma unroll
        for (int m = 0; m < 4; ++m) {
            const int ob = obase + m * 16;
            #pragma unroll
            for (int n = 0; n < 4; ++n) {
                const int l = lbase + n * 16;
                const f32x4 a = acc[m][n];
                #pragma unroll
                for (int jj = 0; jj < 4; ++jj) {
                    const size_t idx = ((size_t)bb * CCH + (ob + jj)) * LEN + l;
                    outf[idx] = sc * a[jj] + bias[ob + jj] + resid[idx];
                }
            }
        }
    }
}

// ---------------------------------------------------------------------------
extern "C" void kernel_launch(void* const* d_in, const int* in_sizes, int n_in,
                              void* d_out, int out_size, void* d_ws, size_t ws_size,
                              hipStream_t stream) {
    const float* x  = (const float*)d_in[0];
    const float* w1 = (const float*)d_in[1];
    const float* b1 = (const float*)d_in[2];
    const float* w2 = (const float*)d_in[3];
    const float* b2 = (const float*)d_in[4];
    const float* g  = (const float*)d_in[5];
    float* out = (float*)d_out;

    char* ws = (char*)d_ws;
    float* sv   = (float*)ws;
    float* part = (float*)(ws + 256);
    u16* wq1   = (u16*)(ws + 4096);
    u16* wq2   = (u16*)(ws + 4096 + 1572864);
    u16* h_t   = (u16*)(ws + 4096 + 2 * 1572864);                 // [16][4098][512] bf16
    u16* h1_t  = (u16*)(ws + 4096 + 2 * 1572864 + 67141632);      // [16][4098][512] bf16

    hipFuncSetAttribute((const void*)conv_gemm13<1>,
                        hipFuncAttributeMaxDynamicSharedMemorySize, 65536);
    hipFuncSetAttribute((const void*)conv_gemm13<2>,
                        hipFuncAttributeMaxDynamicSharedMemorySize, 65536);

    absmean_partial<<<dim3(256), dim3(256), 0, stream>>>(w1, w2, part);
    finalize_scale<<<dim3(1), dim3(256), 0, stream>>>(part, sv);
    quantize_both<<<dim3(3072), dim3(256), 0, stream>>>(w1, w2, sv, wq1, wq2);
    zero_pads<<<dim3(64), dim3(256), 0, stream>>>(h_t, h1_t);
    rms_silu_transpose<<<dim3(2048), dim3(256), 0, stream>>>(x, g, h_t);
    conv_gemm13<1><<<dim3(512), dim3(1024), 65536, stream>>>(h_t, wq1, sv, b1,
                                                             nullptr, h1_t, nullptr);
    conv_gemm13<2><<<dim3(512), dim3(1024), 65536, stream>>>(h1_t, wq2, sv + 1, b2,
                                                             x, nullptr, out);
}

// Round 14
// 321.291 us; speedup vs baseline: 1.0766x; 1.0766x over previous
//
#include <hip/hip_runtime.h>

#define BATCH 16
#define CCH 512
#define LEN 4096
#define LPAD 4098

typedef unsigned short u16;
typedef __bf16 bf16x8 __attribute__((ext_vector_type(8)));
typedef float f32x4 __attribute__((ext_vector_type(4)));
typedef u16 u16x8 __attribute__((ext_vector_type(8)));
typedef u16 u16x4 __attribute__((ext_vector_type(4)));

__device__ __forceinline__ u16 f2bf(float f) {
    unsigned u = __float_as_uint(f);
    u = (u + 0x7fffu + ((u >> 16) & 1u)) >> 16;
    return (u16)u;
}
__device__ __forceinline__ float bf2f(u16 v) {
    return __uint_as_float(((unsigned)v) << 16);
}
__device__ __forceinline__ float silu_f(float v) {
    return v / (1.f + __expf(-v));
}
__device__ __forceinline__ void async16(const u16* g, u16* l) {
    __builtin_amdgcn_global_load_lds(
        (const __attribute__((address_space(1))) unsigned int*)g,
        (__attribute__((address_space(3))) unsigned int*)l, 16, 0, 0);
}

// R14: NO sched_barrier anywhere (m141: order-pinning = -42%).  Memory
// ordering safety comes from the asm "memory" clobbers on the waitcnts.
#define HWBAR() __builtin_amdgcn_s_barrier()
#define WAIT_LGKM0() asm volatile("s_waitcnt lgkmcnt(0)" ::: "memory")
#define WAIT_VM(n) asm volatile("s_waitcnt vmcnt(" #n ")" ::: "memory")

// ---------------------------------------------------------------------------
__global__ __launch_bounds__(256)
void absmean_partial(const float* __restrict__ w1, const float* __restrict__ w2,
                     float* __restrict__ part) {
    const int tid = threadIdx.x;
    const int base = blockIdx.x * 3072;
    float s1 = 0.f, s2 = 0.f;
    for (int i = tid; i < 3072; i += 256) {
        s1 += fabsf(w1[base + i]);
        s2 += fabsf(w2[base + i]);
    }
    __shared__ float r1[256], r2[256];
    r1[tid] = s1; r2[tid] = s2;
    __syncthreads();
    for (int off = 128; off > 0; off >>= 1) {
        if (tid < off) { r1[tid] += r1[tid + off]; r2[tid] += r2[tid + off]; }
        __syncthreads();
    }
    if (tid == 0) { part[blockIdx.x] = r1[0]; part[256 + blockIdx.x] = r2[0]; }
}

__global__ __launch_bounds__(256)
void finalize_scale(const float* __restrict__ part, float* __restrict__ sv) {
    const int tid = threadIdx.x;
    __shared__ float r1[256], r2[256];
    r1[tid] = part[tid]; r2[tid] = part[256 + tid];
    __syncthreads();
    for (int off = 128; off > 0; off >>= 1) {
        if (tid < off) { r1[tid] += r1[tid + off]; r2[tid] += r2[tid + off]; }
        __syncthreads();
    }
    if (tid == 0) {
        sv[0] = fmaxf(r1[0] * (1.f / 786432.f), 1e-5f);
        sv[1] = fmaxf(r2[0] * (1.f / 786432.f), 1e-5f);
    }
}

// ---------------------------------------------------------------------------
__global__ __launch_bounds__(256)
void quantize_both(const float* __restrict__ w1, const float* __restrict__ w2,
                   const float* __restrict__ sv,
                   u16* __restrict__ wq1, u16* __restrict__ wq2) {
    const int idx = blockIdx.x * 256 + threadIdx.x;   // [0, 786432)
    const float s1 = sv[0], s2 = sv[1];
    const int o   = idx / 1536;
    const int rem = idx - o * 1536;
    const int i   = rem / 3;
    const int k   = rem - i * 3;
    const int dst = k * (CCH * CCH) + o * CCH + i;
    float q1 = fmaxf(-1.f, fminf(1.f, rintf(w1[idx] / s1)));
    float q2 = fmaxf(-1.f, fminf(1.f, rintf(w2[idx] / s2)));
    wq1[dst] = f2bf(q1);
    wq2[dst] = f2bf(q2);
}

__global__ __launch_bounds__(256)
void zero_pads(u16* __restrict__ h, u16* __restrict__ h1) {
    const int idx = blockIdx.x * 256 + threadIdx.x;   // [0, 16384)
    const int b = idx >> 10;
    const int r = (idx >> 9) & 1;
    const int i = idx & 511;
    const size_t off = ((size_t)b * LPAD + (r ? (LPAD - 1) : 0)) * CCH + i;
    h[off] = 0;
    h1[off] = 0;
}

// ---------------------------------------------------------------------------
__global__ __launch_bounds__(256)
void rms_silu_transpose(const float* __restrict__ x, const float* __restrict__ g,
                        u16* __restrict__ h_t) {
    __shared__ u16   xt[CCH][33];
    __shared__ float red[8][32];
    __shared__ float rinv[32];
    const int tid = threadIdx.x;
    const int bb  = blockIdx.x >> 7;
    const int l0  = (blockIdx.x & 127) << 5;

    const size_t xbase = (size_t)bb * CCH * LEN + l0;
    {
        const int i_hi = tid >> 3;
        const int l4   = (tid & 7) << 2;
        #pragma unroll
        for (int it = 0; it < 16; ++it) {
            const int i = it * 32 + i_hi;
            const float4 v = *(const float4*)&x[xbase + (size_t)i * LEN + l4];
            xt[i][l4 + 0] = f2bf(v.x);
            xt[i][l4 + 1] = f2bf(v.y);
            xt[i][l4 + 2] = f2bf(v.z);
            xt[i][l4 + 3] = f2bf(v.w);
        }
    }
    __syncthreads();
    {
        const int l = tid & 31, seg = tid >> 5;
        const int ibeg = seg * 64;
        float ss = 0.f;
        #pragma unroll 8
        for (int i = ibeg; i < ibeg + 64; ++i) {
            const float v = bf2f(xt[i][l]);
            ss += v * v;
        }
        red[seg][l] = ss;
    }
    __syncthreads();
    if (tid < 32) {
        float tot = 0.f;
        #pragma unroll
        for (int k2 = 0; k2 < 8; ++k2) tot += red[k2][tid];
        rinv[tid] = rsqrtf(tot * (1.f / 512.f) + 1e-6f);
    }
    __syncthreads();
    {
        const int l  = tid >> 3;
        const int i0 = (tid & 7) << 6;
        const float ri = rinv[l];
        const size_t ob = ((size_t)bb * LPAD + l0 + l + 1) * CCH + i0;
        for (int ii = 0; ii < 64; ii += 8) {
            u16x8 ov;
            #pragma unroll
            for (int jj = 0; jj < 8; ++jj) {
                const int i = i0 + ii + jj;
                float v = bf2f(xt[i][l]) * ri * g[i];
                ov[jj] = f2bf(silu_f(v));
            }
            *(u16x8*)&h_t[ob + ii] = ov;
        }
    }
}

// ---------------------------------------------------------------------------
// Conv-as-GEMM, 8-phase 256x256 template (R4 chassis, sched_barriers REMOVED).
// M=512(o) x N=65536(b,l) x K=24 tiles of 64.  512 threads = 8 waves (2M x 4N),
// per-wave 128x64 output (8x4 16x16x32 frags).  LDS 128 KiB: buf0=even K-tile,
// buf1=odd K-tile, XOR-swizzled (proven 0-conflict).  Counted vmcnt(4) at
// phases 4/8 (max safe depth for this stage->read mapping); raw s_barrier.
template<int EPI>
__global__ __launch_bounds__(512)
void conv_gemm14(const u16* __restrict__ Bsrc, const u16* __restrict__ Wq,
                 const float* __restrict__ sptr, const float* __restrict__ bias,
                 const float* __restrict__ resid, u16* __restrict__ outb,
                 float* __restrict__ outf) {
    extern __shared__ u16 lds[];          // 65536 u16 = 128 KiB
    const int tid  = threadIdx.x;
    const int lane = tid & 63;
    const int wave = tid >> 6;
    const int wm = wave >> 2;             // 0..1  (M half)
    const int wn = wave & 3;              // 0..3  (N quarter)

    // T1: bijective XCD chunking (512 = 8 x 64); mt-pairs share a B-panel.
    const int wgid = (blockIdx.x & 7) * 64 + (blockIdx.x >> 3);
    const int mt = wgid & 1;
    const int nt = wgid >> 1;
    const int o0 = mt << 8;
    const int bb = nt >> 4;
    const int l0 = (nt & 15) << 8;

    // staging geometry: thread -> linear LDS; pre-swizzled source col
    const int sr  = tid >> 3;                              // 0..63
    const int scu = ((tid & 7) << 3) ^ ((sr & 7) << 3);
    const int sdst = tid << 3;

    const u16* aSrcBase = Wq + (size_t)o0 * CCH + scu;
    const u16* bSrcBase = Bsrc + ((size_t)bb * LPAD + l0) * CCH + scu;

    // stage one half-tile: T=0 A, T=1 B; dest buf `pb`; K-tile params ks2/i02
    auto stage = [&](int pb, int T, int h, int ks2, int i02) {
        #pragma unroll
        for (int j = 0; j < 2; ++j) {
            const int r = h * 128 + j * 64 + sr;
            const u16* src = (T == 0)
                ? aSrcBase + ks2 * (CCH * CCH) + r * CCH + i02
                : bSrcBase + (size_t)(r + ks2) * CCH + i02;
            async16(src, &lds[pb * 32768 + T * 16384 + h * 8192 + j * 4096 + sdst]);
        }
    };

    // ds_read geometry (swizzled).  kk=0 cols 0..31, kk=1 cols 32..63.
    const int swz = (lane & 7) << 3;
    const int c0 = ((lane >> 4) << 3) ^ swz;
    const int c1 = (((lane >> 4) << 3) + 32) ^ swz;
    const int aB = wm * 8192 + (lane & 15) * 64;
    const int bB = 16384 + (wn >> 1) * 8192 + ((wn & 1) * 64 + (lane & 15)) * 64;

    bf16x8 ar[4][2], br[4][2];
    f32x4 acc[8][4];
    #pragma unroll
    for (int m = 0; m < 8; ++m)
        #pragma unroll
        for (int n = 0; n < 4; ++n)
            acc[m][n] = (f32x4){0.f, 0.f, 0.f, 0.f};

    auto rdA = [&](int cbuf, int mh) {
        #pragma unroll
        for (int mm = 0; mm < 4; ++mm) {
            const int base = cbuf * 32768 + aB + (mh * 4 + mm) * 1024;
            ar[mm][0] = *(const bf16x8*)&lds[base + c0];
            ar[mm][1] = *(const bf16x8*)&lds[base + c1];
        }
    };
    auto rdB = [&](int cbuf, int nh) {
        #pragma unroll
        for (int nn = 0; nn < 2; ++nn) {
            const int fn = nh * 2 + nn;
            const int base = cbuf * 32768 + bB + fn * 1024;
            br[fn][0] = *(const bf16x8*)&lds[base + c0];
            br[fn][1] = *(const bf16x8*)&lds[base + c1];
        }
    };
    auto mfma16 = [&](int mh, int nh) {
        __builtin_amdgcn_s_setprio(1);
        #pragma unroll
        for (int kk = 0; kk < 2; ++kk)
            #pragma unroll
            for (int mm = 0; mm < 4; ++mm)
                #pragma unroll
                for (int nn = 0; nn < 2; ++nn)
                    acc[mh * 4 + mm][nh * 2 + nn] =
                        __builtin_amdgcn_mfma_f32_16x16x32_bf16(
                            ar[mm][kk], br[nh * 2 + nn][kk],
                            acc[mh * 4 + mm][nh * 2 + nn], 0, 0, 0);
        __builtin_amdgcn_s_setprio(0);
    };

    // prologue: tile0 (A+B) into buf0, tile1-B into buf1
    stage(0, 0, 0, 0, 0);
    stage(0, 0, 1, 0, 0);
    stage(0, 1, 0, 0, 0);
    stage(0, 1, 1, 0, 0);
    stage(1, 1, 0, 0, 64);
    stage(1, 1, 1, 0, 64);
    WAIT_VM(4);
    HWBAR();

    auto iterbody = [&](int j, bool full) {
        const int tO  = 2 * j + 1;
        const int tE2 = 2 * j + 2;
        const int tO2 = 2 * j + 3;
        const int ksO = tO >> 3,  iO  = (tO & 7) << 6;
        const int ksE = tE2 >> 3, iE  = (tE2 & 7) << 6;
        const int ksP = tO2 >> 3, iP  = (tO2 & 7) << 6;
        // ph1: even Q(0,0); stage odd-A-h0
        rdA(0, 0); rdB(0, 0);
        stage(1, 0, 0, ksO, iO);
        HWBAR(); WAIT_LGKM0(); mfma16(0, 0); HWBAR();
        // ph2: Q(0,1); stage odd-A-h1
        rdB(0, 1);
        stage(1, 0, 1, ksO, iO);
        HWBAR(); WAIT_LGKM0(); mfma16(0, 1); HWBAR();
        // ph3: Q(1,1); stage next-even B-h0
        rdA(0, 1);
        if (full) stage(0, 1, 0, ksE, iE);
        HWBAR(); WAIT_LGKM0(); mfma16(1, 1); HWBAR();
        // ph4: Q(1,0); stage next-even B-h1; counted vmcnt
        if (full) stage(0, 1, 1, ksE, iE);
        HWBAR(); mfma16(1, 0);
        if (full) { WAIT_VM(4); } else { WAIT_VM(0); }
        HWBAR();
        // ph5: odd Q(0,0); stage next-even A-h0
        rdA(1, 0); rdB(1, 0);
        if (full) stage(0, 0, 0, ksE, iE);
        HWBAR(); WAIT_LGKM0(); mfma16(0, 0); HWBAR();
        // ph6: Q(0,1); stage next-even A-h1
        rdB(1, 1);
        if (full) stage(0, 0, 1, ksE, iE);
        HWBAR(); WAIT_LGKM0(); mfma16(0, 1); HWBAR();
        // ph7: Q(1,1); stage next-odd B-h0
        rdA(1, 1);
        if (full) stage(1, 1, 0, ksP, iP);
        HWBAR(); WAIT_LGKM0(); mfma16(1, 1); HWBAR();
        // ph8: Q(1,0); stage next-odd B-h1; counted vmcnt
        if (full) stage(1, 1, 1, ksP, iP);
        HWBAR(); mfma16(1, 0);
        if (full) { WAIT_VM(4); }
        HWBAR();
    };

    for (int j = 0; j < 11; ++j) iterbody(j, true);
    iterbody(11, false);

    // epilogue
    const float sc = sptr[0];

    if (EPI == 1) {
        #pragma unroll
        for (int m = 0; m < 8; ++m) {
            const int o_loc = wm * 128 + m * 16 + ((lane >> 4) << 2);
            const int ob = o0 + o_loc;
            const float b0 = bias[ob + 0], b1 = bias[ob + 1];
            const float b2 = bias[ob + 2], b3 = bias[ob + 3];
            #pragma unroll
            for (int n = 0; n < 4; ++n) {
                const int l_loc = wn * 64 + n * 16 + (lane & 15);
                const f32x4 a = acc[m][n];
                u16x4 ov;
                ov[0] = f2bf(silu_f(sc * a[0] + b0));
                ov[1] = f2bf(silu_f(sc * a[1] + b1));
                ov[2] = f2bf(silu_f(sc * a[2] + b2));
                ov[3] = f2bf(silu_f(sc * a[3] + b3));
                char* p = (char*)lds + l_loc * 512 +
                          (((unsigned)(o_loc << 1)) ^ ((l_loc & 7) << 4));
                *(u16x4*)p = ov;
            }
        }
        __syncthreads();
        const int l_r = tid >> 2;            // 0..127
        const int oq  = (tid & 3) << 3;      // u16: 0,8,16,24
        #pragma unroll
        for (int pass = 0; pass < 2; ++pass) {
            const int lr = l_r + pass * 128;
            u16* gdst = outb + ((size_t)bb * LPAD + l0 + lr + 1) * CCH + o0 + oq;
            char* srp = (char*)lds + lr * 512;
            const int swz2 = (lr & 7) << 4;
            #pragma unroll
            for (int c = 0; c < 8; ++c) {
                const uint4 v = *(const uint4*)(srp + (((oq << 1) + c * 64) ^ swz2));
                *(uint4*)(gdst + c * 32) = v;
            }
        }
    } else {
        const int lbase = l0 + wn * 64 + (lane & 15);
        const int obase = o0 + wm * 128 + ((lane >> 4) << 2);
        #pragma unroll
        for (int m = 0; m < 8; ++m) {
            const int ob = obase + m * 16;
            #pragma unroll
            for (int n = 0; n < 4; ++n) {
                const int l = lbase + n * 16;
                const f32x4 a = acc[m][n];
                #pragma unroll
                for (int jj = 0; jj < 4; ++jj) {
                    const size_t idx = ((size_t)bb * CCH + (ob + jj)) * LEN + l;
                    outf[idx] = sc * a[jj] + bias[ob + jj] + resid[idx];
                }
            }
        }
    }
}

// ---------------------------------------------------------------------------
extern "C" void kernel_launch(void* const* d_in, const int* in_sizes, int n_in,
                              void* d_out, int out_size, void* d_ws, size_t ws_size,
                              hipStream_t stream) {
    const float* x  = (const float*)d_in[0];
    const float* w1 = (const float*)d_in[1];
    const float* b1 = (const float*)d_in[2];
    const float* w2 = (const float*)d_in[3];
    const float* b2 = (const float*)d_in[4];
    const float* g  = (const float*)d_in[5];
    float* out = (float*)d_out;

    char* ws = (char*)d_ws;
    float* sv   = (float*)ws;
    float* part = (float*)(ws + 256);
    u16* wq1   = (u16*)(ws + 4096);
    u16* wq2   = (u16*)(ws + 4096 + 1572864);
    u16* h_t   = (u16*)(ws + 4096 + 2 * 1572864);                 // [16][4098][512] bf16
    u16* h1_t  = (u16*)(ws + 4096 + 2 * 1572864 + 67141632);      // [16][4098][512] bf16

    hipFuncSetAttribute((const void*)conv_gemm14<1>,
                        hipFuncAttributeMaxDynamicSharedMemorySize, 131072);
    hipFuncSetAttribute((const void*)conv_gemm14<2>,
                        hipFuncAttributeMaxDynamicSharedMemorySize, 131072);

    absmean_partial<<<dim3(256), dim3(256), 0, stream>>>(w1, w2, part);
    finalize_scale<<<dim3(1), dim3(256), 0, stream>>>(part, sv);
    quantize_both<<<dim3(3072), dim3(256), 0, stream>>>(w1, w2, sv, wq1, wq2);
    zero_pads<<<dim3(64), dim3(256), 0, stream>>>(h_t, h1_t);
    rms_silu_transpose<<<dim3(2048), dim3(256), 0, stream>>>(x, g, h_t);
    conv_gemm14<1><<<dim3(512), dim3(512), 131072, stream>>>(h_t, wq1, sv, b1,
                                                             nullptr, h1_t, nullptr);
    conv_gemm14<2><<<dim3(512), dim3(512), 131072, stream>>>(h1_t, wq2, sv + 1, b2,
                                                             x, nullptr, out);
}